// Round 8
// baseline (609.529 us; speedup 1.0000x reference)
//
#include <hip/hip_runtime.h>
#include <hip/hip_cooperative_groups.h>

#define HH 2048
#define WW 2048
#define NPX (HH*WW)
#define INFV 1e30f
#define TS 128        /* tile size for persistent solver */
#define NT 16         /* tiles per dimension */
#define NTL 256       /* total tiles = blocks */
#define CY 128        /* relax cycles per grid-sync window (even!) */

namespace cg = cooperative_groups;

// raw barrier: LDS-drain only; outstanding global (halo poll) loads stay in flight
__device__ __forceinline__ void BARL(){
  __builtin_amdgcn_sched_barrier(0);
  asm volatile("s_waitcnt lgkmcnt(0)" ::: "memory");
  __builtin_amdgcn_s_barrier();
  __builtin_amdgcn_sched_barrier(0);
}

// ---------- shared math (pinned rounding so every pass computes identical fr) ----------
__device__ __forceinline__ float sobel_at(const float* __restrict__ g, int y, int x){
  float a00,a01,a02,a10,a12,a20,a21,a22;
  if (y>0 && y<HH-1 && x>0 && x<WW-1){
    const float* p = g + (size_t)(y-1)*WW + x;
    a00=p[-1]; a01=p[0]; a02=p[1];
    p += WW;   a10=p[-1];          a12=p[1];
    p += WW;   a20=p[-1]; a21=p[0]; a22=p[1];
  } else {
    auto at=[&](int yy,int xx)->float{
      return (yy<0||yy>=HH||xx<0||xx>=WW)?0.0f:g[(size_t)yy*WW+xx];
    };
    a00=at(y-1,x-1); a01=at(y-1,x); a02=at(y-1,x+1);
    a10=at(y,  x-1);                a12=at(y,  x+1);
    a20=at(y+1,x-1); a21=at(y+1,x); a22=at(y+1,x+1);
  }
  float gx = __fadd_rn(__fadd_rn(__fsub_rn(a02,a00), __fmul_rn(2.0f,__fsub_rn(a12,a10))), __fsub_rn(a22,a20));
  float gy = __fadd_rn(__fadd_rn(__fsub_rn(a20,a00), __fmul_rn(2.0f,__fsub_rn(a21,a01))), __fsub_rn(a22,a02));
  return sqrtf(__fadd_rn(__fmul_rn(gx,gx),__fmul_rn(gy,gy)));
}

// ---------- gray ----------
__global__ void gray_kernel(const float* __restrict__ img, float* __restrict__ gray){
  const float* R=img; const float* G=img+NPX; const float* B=img+2*(size_t)NPX;
  for (int i=blockIdx.x*blockDim.x+threadIdx.x; i<NPX; i+=gridDim.x*blockDim.x){
    gray[i] = __fadd_rn(__fadd_rn(__fmul_rn(0.2989f,R[i]),__fmul_rn(0.587f,G[i])),__fmul_rn(0.114f,B[i]));
  }
}

// ---------- sobel once, cached to fr; level-1 histogram fused ----------
__global__ void sobel_hist1(const float* __restrict__ gray, float* __restrict__ fr,
                            unsigned* __restrict__ hist){
  __shared__ unsigned h[4*2048];
  for (int i=threadIdx.x;i<4*2048;i+=blockDim.x) h[i]=0;
  __syncthreads();
  const int rep=(threadIdx.x&3)*2048;
  for (int i=blockIdx.x*blockDim.x+threadIdx.x; i<NPX; i+=gridDim.x*blockDim.x){
    int y=i>>11, x=i&(WW-1);
    float f=sobel_at(gray,y,x);
    fr[i]=f;
    unsigned key=__float_as_uint(f);
    atomicAdd(&h[rep+(key>>21)],1u);
  }
  __syncthreads();
  for (int i=threadIdx.x;i<2048;i+=blockDim.x){
    unsigned s=h[i]+h[i+2048]+h[i+4096]+h[i+6144];
    if (s) atomicAdd(&hist[i],s);
  }
}

__global__ void hist_l2(const float* __restrict__ fr, const unsigned* __restrict__ sel1,
                        unsigned* __restrict__ hist2){
  __shared__ unsigned h[4*2048];
  __shared__ unsigned sb[4];
  if (threadIdx.x<4) sb[threadIdx.x]=sel1[threadIdx.x];
  for (int i=threadIdx.x;i<4*2048;i+=blockDim.x) h[i]=0;
  __syncthreads();
  for (int i=blockIdx.x*blockDim.x+threadIdx.x; i<NPX; i+=gridDim.x*blockDim.x){
    unsigned key=__float_as_uint(fr[i]);
    unsigned b=key>>21, sub=(key>>10)&0x7FFu;
    #pragma unroll
    for (int k=0;k<4;++k) if (b==sb[k]) atomicAdd(&h[k*2048+sub],1u);
  }
  __syncthreads();
  for (int i=threadIdx.x;i<4*2048;i+=blockDim.x){ unsigned s=h[i]; if (s) atomicAdd(&hist2[i],s); }
}

__global__ void hist_l3(const float* __restrict__ fr, const unsigned* __restrict__ sel1,
                        const unsigned* __restrict__ sel2, unsigned* __restrict__ hist3){
  __shared__ unsigned h[4*1024];
  __shared__ unsigned pf[4];
  if (threadIdx.x<4) pf[threadIdx.x]=(sel1[threadIdx.x]<<11)|sel2[threadIdx.x];
  for (int i=threadIdx.x;i<4*1024;i+=blockDim.x) h[i]=0;
  __syncthreads();
  for (int i=blockIdx.x*blockDim.x+threadIdx.x; i<NPX; i+=gridDim.x*blockDim.x){
    unsigned key=__float_as_uint(fr[i]);
    unsigned p22=key>>10, sub=key&0x3FFu;
    #pragma unroll
    for (int k=0;k<4;++k) if (p22==pf[k]) atomicAdd(&h[k*1024+sub],1u);
  }
  __syncthreads();
  for (int i=threadIdx.x;i<4*1024;i+=blockDim.x){ unsigned s=h[i]; if (s) atomicAdd(&hist3[i],s); }
}

// ranks: floor(0.9825*(n-1))=4120902, floor(0.9925*(n-1))=4162845 (and +1 each)
__global__ void scan_l1(const unsigned* __restrict__ hist, unsigned* __restrict__ sel1,
                        unsigned* __restrict__ rem1){
  __shared__ unsigned part[1024];
  const int t=threadIdx.x;
  unsigned a=hist[2*t], b=hist[2*t+1];
  part[t]=a+b; __syncthreads();
  for (int off=1;off<1024;off<<=1){
    unsigned add=(t>=off)?part[t-off]:0u; __syncthreads();
    part[t]+=add; __syncthreads();
  }
  unsigned before=(t>0)?part[t-1]:0u;
  const unsigned R[4]={4120902u,4120903u,4162845u,4162846u};
  unsigned cum=before;
  #pragma unroll
  for (int i=0;i<4;++i) if (R[i]>=cum && R[i]<cum+a){ sel1[i]=2*t;   rem1[i]=R[i]-cum; }
  cum+=a;
  #pragma unroll
  for (int i=0;i<4;++i) if (R[i]>=cum && R[i]<cum+b){ sel1[i]=2*t+1; rem1[i]=R[i]-cum; }
}

__global__ void scan_l2(const unsigned* __restrict__ hist2, const unsigned* __restrict__ rem1,
                        unsigned* __restrict__ sel2, unsigned* __restrict__ rem2){
  __shared__ unsigned part[1024];
  const int t=threadIdx.x;
  for (int i=0;i<4;++i){
    const unsigned* hh=hist2+i*2048;
    unsigned a=hh[2*t], b=hh[2*t+1];
    part[t]=a+b; __syncthreads();
    for (int off=1;off<1024;off<<=1){
      unsigned add=(t>=off)?part[t-off]:0u; __syncthreads();
      part[t]+=add; __syncthreads();
    }
    unsigned before=(t>0)?part[t-1]:0u;
    unsigned r=rem1[i], cum=before;
    if (r>=cum && r<cum+a){ sel2[i]=2*t;   rem2[i]=r-cum; }
    cum+=a;
    if (r>=cum && r<cum+b){ sel2[i]=2*t+1; rem2[i]=r-cum; }
    __syncthreads();
  }
}

__global__ void scan_l3(const unsigned* __restrict__ hist3, const unsigned* __restrict__ sel1,
                        const unsigned* __restrict__ sel2, const unsigned* __restrict__ rem2,
                        float* __restrict__ scal){
  __shared__ unsigned part[1024];
  __shared__ float vals[4];
  const int t=threadIdx.x;
  for (int i=0;i<4;++i){
    unsigned c=hist3[i*1024+t];
    part[t]=c; __syncthreads();
    for (int off=1;off<1024;off<<=1){
      unsigned add=(t>=off)?part[t-off]:0u; __syncthreads();
      part[t]+=add; __syncthreads();
    }
    unsigned before=(t>0)?part[t-1]:0u;
    unsigned r=rem2[i];
    if (r>=before && r<before+c){
      unsigned key=(sel1[i]<<21)|(sel2[i]<<10)|(unsigned)t;
      vals[i]=__uint_as_float(key);
    }
    __syncthreads();
  }
  if (t==0){
    scal[0]=__fadd_rn(__fmul_rn(vals[0],0.25f),__fmul_rn(vals[1],0.75f));
    scal[1]=__fadd_rn(__fmul_rn(vals[2],0.25f),__fmul_rn(vals[3],0.75f));
  }
}

// ---------- markers -> initial costs ----------
// Field 1 = c1 (seeds: markers==1).  Field 2 = c := min(c1,c2) = flood from the
// UNION of seeds (markers!=0).  c2 < c1  <=>  c < c1 (exact lattice identity).
__global__ void init_cost(const float* __restrict__ gray, const float* frbuf,
                          const float* __restrict__ scal,
                          float* c1out, float* __restrict__ c2out){
  const float qlo=scal[0], qhi=scal[1];
  for (int i=blockIdx.x*blockDim.x+threadIdx.x; i<NPX; i+=gridDim.x*blockDim.x){
    float f=frbuf[i];
    float g=gray[i];
    bool m1 = (f<=qlo);
    bool m2 = (!m1) && (f>=qhi);
    c1out[i] = m1 ? g : INFV;
    c2out[i] = (m1|m2) ? g : INFV;   // union-seed combined field
  }
}

// ---------- persistent-tile cooperative fixed-point solver ----------
// clamp composition: f_cur(f_prev(v)) with f=(lo,hi)->min(hi,max(lo,v)):
//   hi' = min(hi_cur, max(lo_cur, hi_prev)); lo' = max(lo_cur, lo_prev)

#define HSCAN_LR(va,vb,gA,gB,hl) do{ \
  float ql_=gA[j], qh_=va[j]; \
  qh_=fminf(vb[j],fmaxf(gB[j],qh_)); ql_=fmaxf(gB[j],ql_); \
  _Pragma("unroll") \
  for (int d_=1;d_<64;d_<<=1){ \
    float pl_=__shfl_up(ql_,(unsigned)d_), ph_=__shfl_up(qh_,(unsigned)d_); \
    if (c>=d_){ qh_=fminf(qh_,fmaxf(ql_,ph_)); ql_=fmaxf(ql_,pl_); } \
  } \
  float E_=fminf(qh_,fmaxf(ql_,(hl))); \
  float In_=__shfl_up(E_,1u); if(c==0) In_=(hl); \
  float na_=fminf(va[j],fmaxf(gA[j],In_)); if(na_<va[j]){va[j]=na_;ch=true;} \
  float nb_=fminf(vb[j],fmaxf(gB[j],na_)); if(nb_<vb[j]){vb[j]=nb_;ch=true;} \
}while(0)

#define HSCAN_RL(va,vb,gA,gB,hr) do{ \
  float ql_=gB[j], qh_=vb[j]; \
  qh_=fminf(va[j],fmaxf(gA[j],qh_)); ql_=fmaxf(gA[j],ql_); \
  _Pragma("unroll") \
  for (int d_=1;d_<64;d_<<=1){ \
    float pl_=__shfl_down(ql_,(unsigned)d_), ph_=__shfl_down(qh_,(unsigned)d_); \
    if (c+d_<64){ qh_=fminf(qh_,fmaxf(ql_,ph_)); ql_=fmaxf(ql_,pl_); } \
  } \
  float E_=fminf(qh_,fmaxf(ql_,(hr))); \
  float In_=__shfl_down(E_,1u); if(c==63) In_=(hr); \
  float nb_=fminf(vb[j],fmaxf(gB[j],In_)); if(nb_<vb[j]){vb[j]=nb_;ch=true;} \
  float na_=fminf(va[j],fmaxf(gA[j],nb_)); if(na_<va[j]){va[j]=na_;ch=true;} \
}while(0)

#define VCOMP_DN(va,gA,Larr,Harr,XX) { float ql_=gA[0], qh_=va[0]; \
  _Pragma("unroll") for (int jj_=1;jj_<8;++jj_){ qh_=fminf(va[jj_],fmaxf(gA[jj_],qh_)); ql_=fmaxf(gA[jj_],ql_);} \
  Larr[w][XX]=ql_; Harr[w][XX]=qh_; }

#define VCOMP_UP(va,gA,Larr,Harr,XX) { float ql_=gA[7], qh_=va[7]; \
  _Pragma("unroll") for (int jj_=6;jj_>=0;--jj_){ qh_=fminf(va[jj_],fmaxf(gA[jj_],qh_)); ql_=fmaxf(gA[jj_],ql_);} \
  Larr[w][XX]=ql_; Harr[w][XX]=qh_; }

#define VAPPLY_DN(va,gA,Larr,XX) { float In_=Larr[w][XX]; \
  _Pragma("unroll") for (int jj_=0;jj_<8;++jj_){ float nv_=fminf(va[jj_],fmaxf(In_,gA[jj_])); if(nv_<va[jj_]){va[jj_]=nv_;ch=true;} In_=nv_; } }

#define VAPPLY_UP(va,gA,Larr,XX) { float In_=Larr[w][XX]; \
  _Pragma("unroll") for (int jj_=7;jj_>=0;--jj_){ float nv_=fminf(va[jj_],fmaxf(In_,gA[jj_])); if(nv_<va[jj_]){va[jj_]=nv_;ch=true;} In_=nv_; } }

#define CHAIN_DN(Harr,Larr,HT) { float E=HALO[HT][x]; \
  _Pragma("unroll") for (int b_=0;b_<16;++b_){ float I=E; E=fminf(Harr[b_][x],fmaxf(Larr[b_][x],I)); Larr[b_][x]=I; } }

#define CHAIN_UP(Harr,Larr,HB) { float E=HALO[HB][x]; \
  _Pragma("unroll") for (int b_=15;b_>=0;--b_){ float I=E; E=fminf(Harr[b_][x],fmaxf(Larr[b_][x],I)); Larr[b_][x]=I; } }

#define HFIELD(va,vb,IHL,IHR) do{ \
  _Pragma("unroll") \
  for (int j=0;j<8;++j){ \
    const int r_=(w<<3)|j; \
    const float hl=HALO[IHL][r_], hr=HALO[IHR][r_]; \
    { float la_=__shfl_up(vb[j],1u); if(c==0) la_=hl; \
      bool p_=__any((fminf(va[j],fmaxf(la_,ga[j]))<va[j])||(fminf(vb[j],fmaxf(va[j],gb[j]))<vb[j])); \
      if (p_){ HSCAN_LR(va,vb,ga,gb,hl); } } \
    { float ra_=__shfl_down(va[j],1u); if(c==63) ra_=hr; \
      bool p_=__any((fminf(vb[j],fmaxf(ra_,gb[j]))<vb[j])||(fminf(va[j],fmaxf(vb[j],ga[j]))<va[j])); \
      if (p_){ HSCAN_RL(va,vb,ga,gb,hr); } } \
  } \
}while(0)

#define ASTORE(p,v) __hip_atomic_store((p),(v),__ATOMIC_RELAXED,__HIP_MEMORY_SCOPE_AGENT)
#define ALOAD(p)    __hip_atomic_load((p),__ATOMIC_RELAXED,__HIP_MEMORY_SCOPE_AGENT)

// One relax cycle.  HV = this parity's in-flight halo poll register (2-deep
// pipeline: consumed value was loaded 2 cycles ago).  CUR/NXT = flag slots.
// Mechanism-split wake flags (exact):
//   vertical sweep (full dn+up per column) is idempotent -> re-needed only after
//   {H-change, top/bottom halo improve}; horizontal scans (full LR+RL per row)
//   idempotent -> re-needed only after {V-change, left/right halo improve}.
#define CYCLE(HV,CUR,NXT) do{ \
  if (hsrc){ \
    if (HV < HALO[harr][hx]){ \
      HALO[harr][hx]=HV; \
      if (harr<4){ if (harr&1) VN2[NXT]=1; else VN1[NXT]=1; } \
      else       { if (harr&1) HN2[NXT]=1; else HN1[NXT]=1; } \
    } \
    HV=ALOAD(hsrc); \
  } \
  const int vn1=VN1[CUR], hn1=HN1[CUR], vn2=VN2[CUR], hn2=HN2[CUR]; \
  if (!(vn1|hn1|vn2|hn2)){ \
    BARL(); \
  } else { \
    if (vn1){ \
      VCOMP_DN(v1a,ga,DNL1,DNH1,x0) VCOMP_DN(v1b,gb,DNL1,DNH1,x0+1) \
      VCOMP_UP(v1a,ga,UPL1,UPH1,x0) VCOMP_UP(v1b,gb,UPL1,UPH1,x0+1) \
    } \
    if (vn2){ \
      VCOMP_DN(v2a,ga,DNL2,DNH2,x0) VCOMP_DN(v2b,gb,DNL2,DNH2,x0+1) \
      VCOMP_UP(v2a,ga,UPL2,UPH2,x0) VCOMP_UP(v2b,gb,UPL2,UPH2,x0+1) \
    } \
    BARL(); \
    if (w<8){ \
      const int x=((w&1)<<6)|c; \
      const bool go = (w>>2) ? (vn2!=0) : (vn1!=0); \
      if (go){ \
        switch(w>>1){ \
          case 0: CHAIN_DN(DNH1,DNL1,0) break; \
          case 1: CHAIN_UP(UPH1,UPL1,2) break; \
          case 2: CHAIN_DN(DNH2,DNL2,1) break; \
          default:CHAIN_UP(UPH2,UPL2,3) break; \
        } \
      } \
    } \
    BARL(); \
    bool chf1=false, chf2=false; \
    if (vn1){ bool ch=false; \
      VAPPLY_DN(v1a,ga,DNL1,x0) VAPPLY_DN(v1b,gb,DNL1,x0+1) \
      VAPPLY_UP(v1a,ga,UPL1,x0) VAPPLY_UP(v1b,gb,UPL1,x0+1) \
      if (ch){ chf1=true; HN1[NXT]=1; } \
    } \
    if (hn1){ bool ch=false; \
      HFIELD(v1a,v1b,4,6); \
      if (ch){ chf1=true; VN1[NXT]=1; } \
    } \
    if (vn2){ bool ch=false; \
      VAPPLY_DN(v2a,ga,DNL2,x0) VAPPLY_DN(v2b,gb,DNL2,x0+1) \
      VAPPLY_UP(v2a,ga,UPL2,x0) VAPPLY_UP(v2b,gb,UPL2,x0+1) \
      if (ch){ chf2=true; HN2[NXT]=1; } \
    } \
    if (hn2){ bool ch=false; \
      HFIELD(v2a,v2b,5,7); \
      if (ch){ chf2=true; VN2[NXT]=1; } \
    } \
    if (chf1|chf2){ \
      if (w==0){ const int eb=(tile*4+0)*128; \
        if(chf1){ ASTORE(EB1+eb+x0,v1a[0]); ASTORE(EB1+eb+x0+1,v1b[0]); } \
        if(chf2){ ASTORE(EB2+eb+x0,v2a[0]); ASTORE(EB2+eb+x0+1,v2b[0]); } } \
      if (w==15){ const int eb=(tile*4+1)*128; \
        if(chf1){ ASTORE(EB1+eb+x0,v1a[7]); ASTORE(EB1+eb+x0+1,v1b[7]); } \
        if(chf2){ ASTORE(EB2+eb+x0,v2a[7]); ASTORE(EB2+eb+x0+1,v2b[7]); } } \
      if (c==0){ const int eb=(tile*4+2)*128+(w<<3); \
        _Pragma("unroll") \
        for (int j=0;j<8;++j){ if(chf1)ASTORE(EB1+eb+j,v1a[j]); if(chf2)ASTORE(EB2+eb+j,v2a[j]); } } \
      if (c==63){ const int eb=(tile*4+3)*128+(w<<3); \
        _Pragma("unroll") \
        for (int j=0;j<8;++j){ if(chf1)ASTORE(EB1+eb+j,v1b[j]); if(chf2)ASTORE(EB2+eb+j,v2b[j]); } } \
      wflag=1; \
    } \
    if (tid==0){ VN1[CUR]=0; HN1[CUR]=0; VN2[CUR]=0; HN2[CUR]=0; } \
    BARL(); \
  } \
}while(0)

__global__ void __launch_bounds__(1024,4)
ws_solve(float* __restrict__ c1g, const float* __restrict__ grayg, float* outg,
         int* __restrict__ flagIt)
{
  __shared__ float DNL1[16][128], DNH1[16][128], DNL2[16][128], DNH2[16][128];
  __shared__ float UPL1[16][128], UPH1[16][128], UPL2[16][128], UPH2[16][128];
  __shared__ float HALO[8][128];   // 0 Ht1,1 Ht2,2 Hb1,3 Hb2,4 Hl1,5 Hl2,6 Hr1,7 Hr2
  __shared__ int VN1[2],HN1[2],VN2[2],HN2[2];
  __shared__ int wflag;
  cg::grid_group grid = cg::this_grid();
  const int tid=threadIdx.x, w=tid>>6, c=tid&63;
  // XCD-chunked tile mapping (blockIdx%8 ~ XCD round-robin): 4x8-tile region
  // per XCD so most neighbor edge traffic is same-L2. Perf heuristic only.
  const int xcd=blockIdx.x&7, idx=blockIdx.x>>3;
  const int tx=((xcd&3)<<2)|(idx&3), ty=((xcd>>2)<<3)|(idx>>2);
  const int tile=ty*NT+tx;
  const int by=ty*TS, bx=tx*TS, x0=c<<1;
  float* EB1=outg;
  float* EB2=outg+(NTL*4*128);

  // this thread's halo poll slot (1024 threads <-> 8 arrays x 128 entries)
  const int hx=tid&127, harr=tid>>7;
  const float* hsrc=nullptr;
  {
    const float* EB=(harr&1)?EB2:EB1;
    switch(harr>>1){
      case 0: if (ty>0)    hsrc=EB+((tile-NT)*4+1)*128+hx; break;
      case 1: if (ty<NT-1) hsrc=EB+((tile+NT)*4+0)*128+hx; break;
      case 2: if (tx>0)    hsrc=EB+((tile-1)*4+3)*128+hx;  break;
      default:if (tx<NT-1) hsrc=EB+((tile+1)*4+2)*128+hx;  break;
    }
  }

  float v1a[8],v1b[8],v2a[8],v2b[8],ga[8],gb[8];
  {
    size_t base=(size_t)(by+(w<<3))*WW + bx + x0;
    #pragma unroll
    for (int j=0;j<8;++j){
      float2 t1=*(const float2*)(c1g+base);
      float2 t2=*(const float2*)(outg+base);   // field-2 initial lives in d_out
      float2 tg=*(const float2*)(grayg+base);
      v1a[j]=t1.x; v1b[j]=t1.y; v2a[j]=t2.x; v2b[j]=t2.y; ga[j]=tg.x; gb[j]=tg.y;
      base+=(size_t)WW;
    }
  }
  grid.sync();   // all field-2 loads complete before edge buffers overwrite d_out

  // pre-publish initial edges so halos are live from the first cycle
  if (w==0){ const int eb=(tile*4+0)*128;
    ASTORE(EB1+eb+x0,v1a[0]); ASTORE(EB1+eb+x0+1,v1b[0]);
    ASTORE(EB2+eb+x0,v2a[0]); ASTORE(EB2+eb+x0+1,v2b[0]); }
  if (w==15){ const int eb=(tile*4+1)*128;
    ASTORE(EB1+eb+x0,v1a[7]); ASTORE(EB1+eb+x0+1,v1b[7]);
    ASTORE(EB2+eb+x0,v2a[7]); ASTORE(EB2+eb+x0+1,v2b[7]); }
  if (c==0){ const int eb=(tile*4+2)*128+(w<<3);
    #pragma unroll
    for (int j=0;j<8;++j){ ASTORE(EB1+eb+j,v1a[j]); ASTORE(EB2+eb+j,v2a[j]); } }
  if (c==63){ const int eb=(tile*4+3)*128+(w<<3);
    #pragma unroll
    for (int j=0;j<8;++j){ ASTORE(EB1+eb+j,v1b[j]); ASTORE(EB2+eb+j,v2b[j]); } }
  HALO[harr][hx]=INFV;
  if (tid==0){ VN1[0]=1;HN1[0]=1;VN2[0]=1;HN2[0]=1;
               VN1[1]=0;HN1[1]=0;VN2[1]=0;HN2[1]=0; wflag=0; }
  __threadfence();
  grid.sync();

  // 2-deep poll pipeline: hvA consumed at even cycles, hvB at odd
  float hvA=INFV, hvB=INFV;
  if (hsrc){ hvA=ALOAD(hsrc); hvB=ALOAD(hsrc); }

  for (int win=0; win<48; ++win){
    for (int cyc=0; cyc<CY; cyc+=2){
      CYCLE(hvA,0,1);
      CYCLE(hvB,1,0);
    }
    // window end: termination handshake
    if (tid==0 && wflag) atomicMax(flagIt,win+1);
    __threadfence();
    grid.sync();
    int fv=ALOAD(flagIt);
    if (fv<=win) break;   // a full window with zero changes anywhere -> fixed point
    if (tid==0) wflag=0;
    __syncthreads();
  }
  // fused label output: out = (c < c1) ? 1 : 0   (== (c2 < c1))
  {
    size_t base=(size_t)(by+(w<<3))*WW + bx + x0;
    #pragma unroll
    for (int j=0;j<8;++j){
      float2 o; o.x=(v2a[j]<v1a[j])?1.0f:0.0f; o.y=(v2b[j]<v1b[j])?1.0f:0.0f;
      *(float2*)(outg+base)=o;
      base+=(size_t)WW;
    }
  }
}

extern "C" void kernel_launch(void* const* d_in, const int* in_sizes, int n_in,
                              void* d_out, int out_size, void* d_ws, size_t ws_size,
                              hipStream_t stream)
{
  const float* img=(const float*)d_in[0];
  float* out=(float*)d_out;
  char* wsb=(char*)d_ws;
  float* gray=(float*)wsb;
  float* c1  =(float*)(wsb + (size_t)NPX*4);   // doubles as fr cache before init_cost
  unsigned* meta=(unsigned*)(wsb + (size_t)NPX*8);
  float* c2 = out;   // field-2 initial state lives in d_out (fully rewritten each launch)

  unsigned* hist1=meta;            // 2048
  unsigned* hist2=meta+2048;       // 4*2048
  unsigned* hist3=meta+10240;      // 4*1024
  unsigned* sel1 =meta+14336;
  unsigned* rem1 =meta+14340;
  unsigned* sel2 =meta+14344;
  unsigned* rem2 =meta+14348;
  float*    scal =(float*)(meta+14352);   // 2
  int*      flagIt=(int*)(meta+14354);    // 1  -> total 14355 u32

  hipMemsetAsync(meta, 0, 14355*sizeof(unsigned), stream);
  hipLaunchKernelGGL(gray_kernel, dim3(4096), dim3(256), 0, stream, img, gray);
  hipLaunchKernelGGL(sobel_hist1, dim3(1024), dim3(256), 0, stream, gray, c1, hist1);
  hipLaunchKernelGGL(scan_l1, dim3(1), dim3(1024), 0, stream, hist1, sel1, rem1);
  hipLaunchKernelGGL(hist_l2, dim3(1024), dim3(256), 0, stream, c1, sel1, hist2);
  hipLaunchKernelGGL(scan_l2, dim3(1), dim3(1024), 0, stream, hist2, rem1, sel2, rem2);
  hipLaunchKernelGGL(hist_l3, dim3(1024), dim3(256), 0, stream, c1, sel1, sel2, hist3);
  hipLaunchKernelGGL(scan_l3, dim3(1), dim3(1024), 0, stream, hist3, sel1, sel2, rem2, scal);
  hipLaunchKernelGGL(init_cost, dim3(4096), dim3(256), 0, stream, gray, c1, scal, c1, c2);

  void* args[]={ (void*)&c1,(void*)&gray,(void*)&out,(void*)&flagIt };
  (void)hipLaunchCooperativeKernel(ws_solve, dim3(NTL), dim3(1024), args, 0, stream);
}

// Round 9
// 562.080 us; speedup vs baseline: 1.0844x; 1.0844x over previous
//
#include <hip/hip_runtime.h>
#include <hip/hip_cooperative_groups.h>

#define HH 2048
#define WW 2048
#define NPX (HH*WW)
#define INFV 1e30f
#define TS 128        /* tile size for persistent solver */
#define NT 16         /* tiles per dimension */
#define NTL 256       /* total tiles = blocks */
#define CY 32         /* relax cycles per grid-sync window (even!) */

namespace cg = cooperative_groups;

// raw barrier: LDS-drain only; outstanding global (halo poll) loads stay in flight
__device__ __forceinline__ void BARL(){
  __builtin_amdgcn_sched_barrier(0);
  asm volatile("s_waitcnt lgkmcnt(0)" ::: "memory");
  __builtin_amdgcn_s_barrier();
  __builtin_amdgcn_sched_barrier(0);
}

// ---------- shared math (pinned rounding so every pass computes identical fr) ----------
__device__ __forceinline__ float sobel_at(const float* __restrict__ g, int y, int x){
  float a00,a01,a02,a10,a12,a20,a21,a22;
  if (y>0 && y<HH-1 && x>0 && x<WW-1){
    const float* p = g + (size_t)(y-1)*WW + x;
    a00=p[-1]; a01=p[0]; a02=p[1];
    p += WW;   a10=p[-1];          a12=p[1];
    p += WW;   a20=p[-1]; a21=p[0]; a22=p[1];
  } else {
    auto at=[&](int yy,int xx)->float{
      return (yy<0||yy>=HH||xx<0||xx>=WW)?0.0f:g[(size_t)yy*WW+xx];
    };
    a00=at(y-1,x-1); a01=at(y-1,x); a02=at(y-1,x+1);
    a10=at(y,  x-1);                a12=at(y,  x+1);
    a20=at(y+1,x-1); a21=at(y+1,x); a22=at(y+1,x+1);
  }
  float gx = __fadd_rn(__fadd_rn(__fsub_rn(a02,a00), __fmul_rn(2.0f,__fsub_rn(a12,a10))), __fsub_rn(a22,a20));
  float gy = __fadd_rn(__fadd_rn(__fsub_rn(a20,a00), __fmul_rn(2.0f,__fsub_rn(a21,a01))), __fsub_rn(a22,a02));
  return sqrtf(__fadd_rn(__fmul_rn(gx,gx),__fmul_rn(gy,gy)));
}

// ---------- gray ----------
__global__ void gray_kernel(const float* __restrict__ img, float* __restrict__ gray){
  const float* R=img; const float* G=img+NPX; const float* B=img+2*(size_t)NPX;
  for (int i=blockIdx.x*blockDim.x+threadIdx.x; i<NPX; i+=gridDim.x*blockDim.x){
    gray[i] = __fadd_rn(__fadd_rn(__fmul_rn(0.2989f,R[i]),__fmul_rn(0.587f,G[i])),__fmul_rn(0.114f,B[i]));
  }
}

// ---------- sobel once, cached to fr; level-1 histogram fused ----------
__global__ void sobel_hist1(const float* __restrict__ gray, float* __restrict__ fr,
                            unsigned* __restrict__ hist){
  __shared__ unsigned h[4*2048];
  for (int i=threadIdx.x;i<4*2048;i+=blockDim.x) h[i]=0;
  __syncthreads();
  const int rep=(threadIdx.x&3)*2048;
  for (int i=blockIdx.x*blockDim.x+threadIdx.x; i<NPX; i+=gridDim.x*blockDim.x){
    int y=i>>11, x=i&(WW-1);
    float f=sobel_at(gray,y,x);
    fr[i]=f;
    unsigned key=__float_as_uint(f);
    atomicAdd(&h[rep+(key>>21)],1u);
  }
  __syncthreads();
  for (int i=threadIdx.x;i<2048;i+=blockDim.x){
    unsigned s=h[i]+h[i+2048]+h[i+4096]+h[i+6144];
    if (s) atomicAdd(&hist[i],s);
  }
}

__global__ void hist_l2(const float* __restrict__ fr, const unsigned* __restrict__ sel1,
                        unsigned* __restrict__ hist2){
  __shared__ unsigned h[4*2048];
  __shared__ unsigned sb[4];
  if (threadIdx.x<4) sb[threadIdx.x]=sel1[threadIdx.x];
  for (int i=threadIdx.x;i<4*2048;i+=blockDim.x) h[i]=0;
  __syncthreads();
  for (int i=blockIdx.x*blockDim.x+threadIdx.x; i<NPX; i+=gridDim.x*blockDim.x){
    unsigned key=__float_as_uint(fr[i]);
    unsigned b=key>>21, sub=(key>>10)&0x7FFu;
    #pragma unroll
    for (int k=0;k<4;++k) if (b==sb[k]) atomicAdd(&h[k*2048+sub],1u);
  }
  __syncthreads();
  for (int i=threadIdx.x;i<4*2048;i+=blockDim.x){ unsigned s=h[i]; if (s) atomicAdd(&hist2[i],s); }
}

__global__ void hist_l3(const float* __restrict__ fr, const unsigned* __restrict__ sel1,
                        const unsigned* __restrict__ sel2, unsigned* __restrict__ hist3){
  __shared__ unsigned h[4*1024];
  __shared__ unsigned pf[4];
  if (threadIdx.x<4) pf[threadIdx.x]=(sel1[threadIdx.x]<<11)|sel2[threadIdx.x];
  for (int i=threadIdx.x;i<4*1024;i+=blockDim.x) h[i]=0;
  __syncthreads();
  for (int i=blockIdx.x*blockDim.x+threadIdx.x; i<NPX; i+=gridDim.x*blockDim.x){
    unsigned key=__float_as_uint(fr[i]);
    unsigned p22=key>>10, sub=key&0x3FFu;
    #pragma unroll
    for (int k=0;k<4;++k) if (p22==pf[k]) atomicAdd(&h[k*1024+sub],1u);
  }
  __syncthreads();
  for (int i=threadIdx.x;i<4*1024;i+=blockDim.x){ unsigned s=h[i]; if (s) atomicAdd(&hist3[i],s); }
}

// ranks: floor(0.9825*(n-1))=4120902, floor(0.9925*(n-1))=4162845 (and +1 each)
__global__ void scan_l1(const unsigned* __restrict__ hist, unsigned* __restrict__ sel1,
                        unsigned* __restrict__ rem1){
  __shared__ unsigned part[1024];
  const int t=threadIdx.x;
  unsigned a=hist[2*t], b=hist[2*t+1];
  part[t]=a+b; __syncthreads();
  for (int off=1;off<1024;off<<=1){
    unsigned add=(t>=off)?part[t-off]:0u; __syncthreads();
    part[t]+=add; __syncthreads();
  }
  unsigned before=(t>0)?part[t-1]:0u;
  const unsigned R[4]={4120902u,4120903u,4162845u,4162846u};
  unsigned cum=before;
  #pragma unroll
  for (int i=0;i<4;++i) if (R[i]>=cum && R[i]<cum+a){ sel1[i]=2*t;   rem1[i]=R[i]-cum; }
  cum+=a;
  #pragma unroll
  for (int i=0;i<4;++i) if (R[i]>=cum && R[i]<cum+b){ sel1[i]=2*t+1; rem1[i]=R[i]-cum; }
}

__global__ void scan_l2(const unsigned* __restrict__ hist2, const unsigned* __restrict__ rem1,
                        unsigned* __restrict__ sel2, unsigned* __restrict__ rem2){
  __shared__ unsigned part[1024];
  const int t=threadIdx.x;
  for (int i=0;i<4;++i){
    const unsigned* hh=hist2+i*2048;
    unsigned a=hh[2*t], b=hh[2*t+1];
    part[t]=a+b; __syncthreads();
    for (int off=1;off<1024;off<<=1){
      unsigned add=(t>=off)?part[t-off]:0u; __syncthreads();
      part[t]+=add; __syncthreads();
    }
    unsigned before=(t>0)?part[t-1]:0u;
    unsigned r=rem1[i], cum=before;
    if (r>=cum && r<cum+a){ sel2[i]=2*t;   rem2[i]=r-cum; }
    cum+=a;
    if (r>=cum && r<cum+b){ sel2[i]=2*t+1; rem2[i]=r-cum; }
    __syncthreads();
  }
}

__global__ void scan_l3(const unsigned* __restrict__ hist3, const unsigned* __restrict__ sel1,
                        const unsigned* __restrict__ sel2, const unsigned* __restrict__ rem2,
                        float* __restrict__ scal){
  __shared__ unsigned part[1024];
  __shared__ float vals[4];
  const int t=threadIdx.x;
  for (int i=0;i<4;++i){
    unsigned c=hist3[i*1024+t];
    part[t]=c; __syncthreads();
    for (int off=1;off<1024;off<<=1){
      unsigned add=(t>=off)?part[t-off]:0u; __syncthreads();
      part[t]+=add; __syncthreads();
    }
    unsigned before=(t>0)?part[t-1]:0u;
    unsigned r=rem2[i];
    if (r>=before && r<before+c){
      unsigned key=(sel1[i]<<21)|(sel2[i]<<10)|(unsigned)t;
      vals[i]=__uint_as_float(key);
    }
    __syncthreads();
  }
  if (t==0){
    scal[0]=__fadd_rn(__fmul_rn(vals[0],0.25f),__fmul_rn(vals[1],0.75f));
    scal[1]=__fadd_rn(__fmul_rn(vals[2],0.25f),__fmul_rn(vals[3],0.75f));
  }
}

// ---------- markers -> initial costs ----------
// Field 1 = c1 (seeds: markers==1).  Field 2 = c := min(c1,c2) = flood from the
// UNION of seeds (markers!=0).  c2 < c1  <=>  c < c1 (exact lattice identity).
__global__ void init_cost(const float* __restrict__ gray, const float* frbuf,
                          const float* __restrict__ scal,
                          float* c1out, float* __restrict__ c2out){
  const float qlo=scal[0], qhi=scal[1];
  for (int i=blockIdx.x*blockDim.x+threadIdx.x; i<NPX; i+=gridDim.x*blockDim.x){
    float f=frbuf[i];
    float g=gray[i];
    bool m1 = (f<=qlo);
    bool m2 = (!m1) && (f>=qhi);
    c1out[i] = m1 ? g : INFV;
    c2out[i] = (m1|m2) ? g : INFV;   // union-seed combined field
  }
}

// ---------- clamp-scan machinery (shared by tile_solve and ws_solve) ----------
// clamp composition: f_cur(f_prev(v)) with f=(lo,hi)->min(hi,max(lo,v)):
//   hi' = min(hi_cur, max(lo_cur, hi_prev)); lo' = max(lo_cur, lo_prev)

#define HSCAN_LR(va,vb,gA,gB,hl) do{ \
  float ql_=gA[j], qh_=va[j]; \
  qh_=fminf(vb[j],fmaxf(gB[j],qh_)); ql_=fmaxf(gB[j],ql_); \
  _Pragma("unroll") \
  for (int d_=1;d_<64;d_<<=1){ \
    float pl_=__shfl_up(ql_,(unsigned)d_), ph_=__shfl_up(qh_,(unsigned)d_); \
    if (c>=d_){ qh_=fminf(qh_,fmaxf(ql_,ph_)); ql_=fmaxf(ql_,pl_); } \
  } \
  float E_=fminf(qh_,fmaxf(ql_,(hl))); \
  float In_=__shfl_up(E_,1u); if(c==0) In_=(hl); \
  float na_=fminf(va[j],fmaxf(gA[j],In_)); if(na_<va[j]){va[j]=na_;ch=true;} \
  float nb_=fminf(vb[j],fmaxf(gB[j],na_)); if(nb_<vb[j]){vb[j]=nb_;ch=true;} \
}while(0)

#define HSCAN_RL(va,vb,gA,gB,hr) do{ \
  float ql_=gB[j], qh_=vb[j]; \
  qh_=fminf(va[j],fmaxf(gA[j],qh_)); ql_=fmaxf(gA[j],ql_); \
  _Pragma("unroll") \
  for (int d_=1;d_<64;d_<<=1){ \
    float pl_=__shfl_down(ql_,(unsigned)d_), ph_=__shfl_down(qh_,(unsigned)d_); \
    if (c+d_<64){ qh_=fminf(qh_,fmaxf(ql_,ph_)); ql_=fmaxf(ql_,pl_); } \
  } \
  float E_=fminf(qh_,fmaxf(ql_,(hr))); \
  float In_=__shfl_down(E_,1u); if(c==63) In_=(hr); \
  float nb_=fminf(vb[j],fmaxf(gB[j],In_)); if(nb_<vb[j]){vb[j]=nb_;ch=true;} \
  float na_=fminf(va[j],fmaxf(gA[j],nb_)); if(na_<va[j]){va[j]=na_;ch=true;} \
}while(0)

#define VCOMP_DN(va,gA,Larr,Harr,XX) { float ql_=gA[0], qh_=va[0]; \
  _Pragma("unroll") for (int jj_=1;jj_<8;++jj_){ qh_=fminf(va[jj_],fmaxf(gA[jj_],qh_)); ql_=fmaxf(gA[jj_],ql_);} \
  Larr[w][XX]=ql_; Harr[w][XX]=qh_; }

#define VCOMP_UP(va,gA,Larr,Harr,XX) { float ql_=gA[7], qh_=va[7]; \
  _Pragma("unroll") for (int jj_=6;jj_>=0;--jj_){ qh_=fminf(va[jj_],fmaxf(gA[jj_],qh_)); ql_=fmaxf(gA[jj_],ql_);} \
  Larr[w][XX]=ql_; Harr[w][XX]=qh_; }

#define VAPPLY_DN(va,gA,Larr,XX) { float In_=Larr[w][XX]; \
  _Pragma("unroll") for (int jj_=0;jj_<8;++jj_){ float nv_=fminf(va[jj_],fmaxf(In_,gA[jj_])); if(nv_<va[jj_]){va[jj_]=nv_;ch=true;} In_=nv_; } }

#define VAPPLY_UP(va,gA,Larr,XX) { float In_=Larr[w][XX]; \
  _Pragma("unroll") for (int jj_=7;jj_>=0;--jj_){ float nv_=fminf(va[jj_],fmaxf(In_,gA[jj_])); if(nv_<va[jj_]){va[jj_]=nv_;ch=true;} In_=nv_; } }

#define CHAIN_DN(Harr,Larr,HT) { float E=HALO[HT][x]; \
  _Pragma("unroll") for (int b_=0;b_<16;++b_){ float I=E; E=fminf(Harr[b_][x],fmaxf(Larr[b_][x],I)); Larr[b_][x]=I; } }

#define CHAIN_UP(Harr,Larr,HB) { float E=HALO[HB][x]; \
  _Pragma("unroll") for (int b_=15;b_>=0;--b_){ float I=E; E=fminf(Harr[b_][x],fmaxf(Larr[b_][x],I)); Larr[b_][x]=I; } }

#define HFIELD(va,vb,IHL,IHR) do{ \
  _Pragma("unroll") \
  for (int j=0;j<8;++j){ \
    const int r_=(w<<3)|j; \
    const float hl=HALO[IHL][r_], hr=HALO[IHR][r_]; \
    { float la_=__shfl_up(vb[j],1u); if(c==0) la_=hl; \
      bool p_=__any((fminf(va[j],fmaxf(la_,ga[j]))<va[j])||(fminf(vb[j],fmaxf(va[j],gb[j]))<vb[j])); \
      if (p_){ HSCAN_LR(va,vb,ga,gb,hl); } } \
    { float ra_=__shfl_down(va[j],1u); if(c==63) ra_=hr; \
      bool p_=__any((fminf(vb[j],fmaxf(ra_,gb[j]))<vb[j])||(fminf(va[j],fmaxf(vb[j],ga[j]))<va[j])); \
      if (p_){ HSCAN_RL(va,vb,ga,gb,hr); } } \
  } \
}while(0)

#define ASTORE(p,v) __hip_atomic_store((p),(v),__ATOMIC_RELAXED,__HIP_MEMORY_SCOPE_AGENT)
#define ALOAD(p)    __hip_atomic_load((p),__ATOMIC_RELAXED,__HIP_MEMORY_SCOPE_AGENT)

// ---------- one-pass pre-solver ----------
// 1024 blocks; each solves a 128x128 WINDOW (64x64 output + 32px halo ring) to
// window-local convergence (INF outside window), stores the interior only.
// Seeds never change under relaxation -> the fixed point is per-gap-cluster
// local; clusters (iid, <=1.75% unseeded) have diameter << 32, so interiors are
// exact except for improbable giants. ws_solve then verifies & repairs (sound
// regardless). Concurrent interior-store vs halo-read between blocks is
// monotone-safe: 4B-granular, values only decrease, any mix is a valid state.
__global__ void __launch_bounds__(1024,4)
tile_solve(float* __restrict__ c1g, float* __restrict__ cg, const float* __restrict__ grayg)
{
  __shared__ float DNL1[16][128], DNH1[16][128], DNL2[16][128], DNH2[16][128];
  __shared__ float UPL1[16][128], UPH1[16][128], UPL2[16][128], UPH2[16][128];
  __shared__ float HALO[8][128];
  __shared__ int VN1[2],HN1[2],VN2[2],HN2[2];
  const int tid=threadIdx.x, w=tid>>6, c=tid&63;
  const int oty=blockIdx.x>>5, otx=blockIdx.x&31;
  const int wy0=oty*64-32, wx0=otx*64-32, x0=c<<1;
  HALO[tid>>7][tid&127]=INFV;
  if (tid==0){ VN1[0]=1;HN1[0]=1;VN2[0]=1;HN2[0]=1;
               VN1[1]=0;HN1[1]=0;VN2[1]=0;HN2[1]=0; }
  float v1a[8],v1b[8],v2a[8],v2b[8],ga[8],gb[8];
  const int gx=wx0+x0;
  const bool cok=(gx>=0)&&(gx+1<WW);
  #pragma unroll
  for (int j=0;j<8;++j){
    const int gy=wy0+(w<<3)+j;
    const bool rok=(gy>=0)&&(gy<HH);
    if (rok&&cok){
      const size_t b=(size_t)gy*WW+gx;
      float2 t1=*(const float2*)(c1g+b);
      float2 t2=*(const float2*)(cg+b);
      float2 tg=*(const float2*)(grayg+b);
      v1a[j]=t1.x; v1b[j]=t1.y; v2a[j]=t2.x; v2b[j]=t2.y; ga[j]=tg.x; gb[j]=tg.y;
    } else if (rok){
      const bool aok=(gx>=0)&&(gx<WW), bok=(gx+1>=0)&&(gx+1<WW);
      const size_t b=(size_t)gy*WW;
      v1a[j]=aok?c1g[b+gx]:INFV;   v1b[j]=bok?c1g[b+gx+1]:INFV;
      v2a[j]=aok?cg [b+gx]:INFV;   v2b[j]=bok?cg [b+gx+1]:INFV;
      ga [j]=aok?grayg[b+gx]:INFV; gb [j]=bok?grayg[b+gx+1]:INFV;
    } else {
      v1a[j]=INFV;v1b[j]=INFV;v2a[j]=INFV;v2b[j]=INFV;ga[j]=INFV;gb[j]=INFV;
    }
  }
  __syncthreads();
  for (int cyc=0; cyc<64; ++cyc){
    const int cur=cyc&1, nxt=cur^1;
    const int vn1=VN1[cur], hn1=HN1[cur], vn2=VN2[cur], hn2=HN2[cur];
    if (!(vn1|hn1|vn2|hn2)) break;
    if (vn1){
      VCOMP_DN(v1a,ga,DNL1,DNH1,x0) VCOMP_DN(v1b,gb,DNL1,DNH1,x0+1)
      VCOMP_UP(v1a,ga,UPL1,UPH1,x0) VCOMP_UP(v1b,gb,UPL1,UPH1,x0+1)
    }
    if (vn2){
      VCOMP_DN(v2a,ga,DNL2,DNH2,x0) VCOMP_DN(v2b,gb,DNL2,DNH2,x0+1)
      VCOMP_UP(v2a,ga,UPL2,UPH2,x0) VCOMP_UP(v2b,gb,UPL2,UPH2,x0+1)
    }
    __syncthreads();
    if (w<8){
      const int x=((w&1)<<6)|c;
      const bool go=(w>>2)?(vn2!=0):(vn1!=0);
      if (go){
        switch(w>>1){
          case 0: CHAIN_DN(DNH1,DNL1,0) break;
          case 1: CHAIN_UP(UPH1,UPL1,2) break;
          case 2: CHAIN_DN(DNH2,DNL2,1) break;
          default:CHAIN_UP(UPH2,UPL2,3) break;
        }
      }
    }
    __syncthreads();
    if (vn1){ bool ch=false;
      VAPPLY_DN(v1a,ga,DNL1,x0) VAPPLY_DN(v1b,gb,DNL1,x0+1)
      VAPPLY_UP(v1a,ga,UPL1,x0) VAPPLY_UP(v1b,gb,UPL1,x0+1)
      if (ch) HN1[nxt]=1;
    }
    if (hn1){ bool ch=false;
      HFIELD(v1a,v1b,4,6);
      if (ch) VN1[nxt]=1;
    }
    if (vn2){ bool ch=false;
      VAPPLY_DN(v2a,ga,DNL2,x0) VAPPLY_DN(v2b,gb,DNL2,x0+1)
      VAPPLY_UP(v2a,ga,UPL2,x0) VAPPLY_UP(v2b,gb,UPL2,x0+1)
      if (ch) HN2[nxt]=1;
    }
    if (hn2){ bool ch=false;
      HFIELD(v2a,v2b,5,7);
      if (ch) VN2[nxt]=1;
    }
    if (tid==0){ VN1[cur]=0; HN1[cur]=0; VN2[cur]=0; HN2[cur]=0; }
    __syncthreads();
  }
  // store the 64x64 interior (window rows 32..95 <-> w in [4,12); cols via c in [16,48))
  if (w>=4 && w<12 && c>=16 && c<48){
    #pragma unroll
    for (int j=0;j<8;++j){
      const int gy=wy0+(w<<3)+j;
      const size_t b=(size_t)gy*WW+gx;
      float2 o1; o1.x=v1a[j]; o1.y=v1b[j];
      float2 o2; o2.x=v2a[j]; o2.y=v2b[j];
      *(float2*)(c1g+b)=o1;
      *(float2*)(cg +b)=o2;
    }
  }
}

// ---------- persistent-tile cooperative verifier/cleanup ----------
// One relax cycle.  HV = this parity's in-flight halo poll register (2-deep
// pipeline).  Mechanism-split wake flags (vertical sweep idempotent ->
// re-needed only after H-change / top-bottom halo improve; and vice versa).
#define CYCLE(HV,CUR,NXT) do{ \
  if (hsrc){ \
    if (HV < HALO[harr][hx]){ \
      HALO[harr][hx]=HV; \
      if (harr<4){ if (harr&1) VN2[NXT]=1; else VN1[NXT]=1; } \
      else       { if (harr&1) HN2[NXT]=1; else HN1[NXT]=1; } \
    } \
    HV=ALOAD(hsrc); \
  } \
  const int vn1=VN1[CUR], hn1=HN1[CUR], vn2=VN2[CUR], hn2=HN2[CUR]; \
  if (!(vn1|hn1|vn2|hn2)){ \
    BARL(); \
  } else { \
    if (vn1){ \
      VCOMP_DN(v1a,ga,DNL1,DNH1,x0) VCOMP_DN(v1b,gb,DNL1,DNH1,x0+1) \
      VCOMP_UP(v1a,ga,UPL1,UPH1,x0) VCOMP_UP(v1b,gb,UPL1,UPH1,x0+1) \
    } \
    if (vn2){ \
      VCOMP_DN(v2a,ga,DNL2,DNH2,x0) VCOMP_DN(v2b,gb,DNL2,DNH2,x0+1) \
      VCOMP_UP(v2a,ga,UPL2,UPH2,x0) VCOMP_UP(v2b,gb,UPL2,UPH2,x0+1) \
    } \
    BARL(); \
    if (w<8){ \
      const int x=((w&1)<<6)|c; \
      const bool go = (w>>2) ? (vn2!=0) : (vn1!=0); \
      if (go){ \
        switch(w>>1){ \
          case 0: CHAIN_DN(DNH1,DNL1,0) break; \
          case 1: CHAIN_UP(UPH1,UPL1,2) break; \
          case 2: CHAIN_DN(DNH2,DNL2,1) break; \
          default:CHAIN_UP(UPH2,UPL2,3) break; \
        } \
      } \
    } \
    BARL(); \
    bool chf1=false, chf2=false; \
    if (vn1){ bool ch=false; \
      VAPPLY_DN(v1a,ga,DNL1,x0) VAPPLY_DN(v1b,gb,DNL1,x0+1) \
      VAPPLY_UP(v1a,ga,UPL1,x0) VAPPLY_UP(v1b,gb,UPL1,x0+1) \
      if (ch){ chf1=true; HN1[NXT]=1; } \
    } \
    if (hn1){ bool ch=false; \
      HFIELD(v1a,v1b,4,6); \
      if (ch){ chf1=true; VN1[NXT]=1; } \
    } \
    if (vn2){ bool ch=false; \
      VAPPLY_DN(v2a,ga,DNL2,x0) VAPPLY_DN(v2b,gb,DNL2,x0+1) \
      VAPPLY_UP(v2a,ga,UPL2,x0) VAPPLY_UP(v2b,gb,UPL2,x0+1) \
      if (ch){ chf2=true; HN2[NXT]=1; } \
    } \
    if (hn2){ bool ch=false; \
      HFIELD(v2a,v2b,5,7); \
      if (ch){ chf2=true; VN2[NXT]=1; } \
    } \
    if (chf1|chf2){ \
      if (w==0){ const int eb=(tile*4+0)*128; \
        if(chf1){ ASTORE(EB1+eb+x0,v1a[0]); ASTORE(EB1+eb+x0+1,v1b[0]); } \
        if(chf2){ ASTORE(EB2+eb+x0,v2a[0]); ASTORE(EB2+eb+x0+1,v2b[0]); } } \
      if (w==15){ const int eb=(tile*4+1)*128; \
        if(chf1){ ASTORE(EB1+eb+x0,v1a[7]); ASTORE(EB1+eb+x0+1,v1b[7]); } \
        if(chf2){ ASTORE(EB2+eb+x0,v2a[7]); ASTORE(EB2+eb+x0+1,v2b[7]); } } \
      if (c==0){ const int eb=(tile*4+2)*128+(w<<3); \
        _Pragma("unroll") \
        for (int j=0;j<8;++j){ if(chf1)ASTORE(EB1+eb+j,v1a[j]); if(chf2)ASTORE(EB2+eb+j,v2a[j]); } } \
      if (c==63){ const int eb=(tile*4+3)*128+(w<<3); \
        _Pragma("unroll") \
        for (int j=0;j<8;++j){ if(chf1)ASTORE(EB1+eb+j,v1b[j]); if(chf2)ASTORE(EB2+eb+j,v2b[j]); } } \
      wflag=1; \
    } \
    if (tid==0){ VN1[CUR]=0; HN1[CUR]=0; VN2[CUR]=0; HN2[CUR]=0; } \
    BARL(); \
  } \
}while(0)

__global__ void __launch_bounds__(1024,4)
ws_solve(float* __restrict__ c1g, const float* __restrict__ grayg, float* outg,
         int* __restrict__ flagIt)
{
  __shared__ float DNL1[16][128], DNH1[16][128], DNL2[16][128], DNH2[16][128];
  __shared__ float UPL1[16][128], UPH1[16][128], UPL2[16][128], UPH2[16][128];
  __shared__ float HALO[8][128];   // 0 Ht1,1 Ht2,2 Hb1,3 Hb2,4 Hl1,5 Hl2,6 Hr1,7 Hr2
  __shared__ int VN1[2],HN1[2],VN2[2],HN2[2];
  __shared__ int wflag;
  cg::grid_group grid = cg::this_grid();
  const int tid=threadIdx.x, w=tid>>6, c=tid&63;
  // XCD-chunked tile mapping (blockIdx%8 ~ XCD round-robin): 4x8-tile region
  // per XCD so most neighbor edge traffic is same-L2. Perf heuristic only.
  const int xcd=blockIdx.x&7, idx=blockIdx.x>>3;
  const int tx=((xcd&3)<<2)|(idx&3), ty=((xcd>>2)<<3)|(idx>>2);
  const int tile=ty*NT+tx;
  const int by=ty*TS, bx=tx*TS, x0=c<<1;
  float* EB1=outg;
  float* EB2=outg+(NTL*4*128);

  // this thread's halo poll slot (1024 threads <-> 8 arrays x 128 entries)
  const int hx=tid&127, harr=tid>>7;
  const float* hsrc=nullptr;
  {
    const float* EB=(harr&1)?EB2:EB1;
    switch(harr>>1){
      case 0: if (ty>0)    hsrc=EB+((tile-NT)*4+1)*128+hx; break;
      case 1: if (ty<NT-1) hsrc=EB+((tile+NT)*4+0)*128+hx; break;
      case 2: if (tx>0)    hsrc=EB+((tile-1)*4+3)*128+hx;  break;
      default:if (tx<NT-1) hsrc=EB+((tile+1)*4+2)*128+hx;  break;
    }
  }

  float v1a[8],v1b[8],v2a[8],v2b[8],ga[8],gb[8];
  {
    size_t base=(size_t)(by+(w<<3))*WW + bx + x0;
    #pragma unroll
    for (int j=0;j<8;++j){
      float2 t1=*(const float2*)(c1g+base);
      float2 t2=*(const float2*)(outg+base);   // field-2 state lives in d_out
      float2 tg=*(const float2*)(grayg+base);
      v1a[j]=t1.x; v1b[j]=t1.y; v2a[j]=t2.x; v2b[j]=t2.y; ga[j]=tg.x; gb[j]=tg.y;
      base+=(size_t)WW;
    }
  }
  grid.sync();   // all field-2 loads complete before edge buffers overwrite d_out

  // pre-publish initial edges so halos are live from the first cycle
  if (w==0){ const int eb=(tile*4+0)*128;
    ASTORE(EB1+eb+x0,v1a[0]); ASTORE(EB1+eb+x0+1,v1b[0]);
    ASTORE(EB2+eb+x0,v2a[0]); ASTORE(EB2+eb+x0+1,v2b[0]); }
  if (w==15){ const int eb=(tile*4+1)*128;
    ASTORE(EB1+eb+x0,v1a[7]); ASTORE(EB1+eb+x0+1,v1b[7]);
    ASTORE(EB2+eb+x0,v2a[7]); ASTORE(EB2+eb+x0+1,v2b[7]); }
  if (c==0){ const int eb=(tile*4+2)*128+(w<<3);
    #pragma unroll
    for (int j=0;j<8;++j){ ASTORE(EB1+eb+j,v1a[j]); ASTORE(EB2+eb+j,v2a[j]); } }
  if (c==63){ const int eb=(tile*4+3)*128+(w<<3);
    #pragma unroll
    for (int j=0;j<8;++j){ ASTORE(EB1+eb+j,v1b[j]); ASTORE(EB2+eb+j,v2b[j]); } }
  HALO[harr][hx]=INFV;
  if (tid==0){ VN1[0]=1;HN1[0]=1;VN2[0]=1;HN2[0]=1;
               VN1[1]=0;HN1[1]=0;VN2[1]=0;HN2[1]=0; wflag=0; }
  __threadfence();
  grid.sync();

  // 2-deep poll pipeline: hvA consumed at even cycles, hvB at odd
  float hvA=INFV, hvB=INFV;
  if (hsrc){ hvA=ALOAD(hsrc); hvB=ALOAD(hsrc); }

  for (int win=0; win<96; ++win){
    for (int cyc=0; cyc<CY; cyc+=2){
      CYCLE(hvA,0,1);
      CYCLE(hvB,1,0);
    }
    // window end: termination handshake
    if (tid==0 && wflag) atomicMax(flagIt,win+1);
    __threadfence();
    grid.sync();
    int fv=ALOAD(flagIt);
    if (fv<=win) break;   // a full window with zero changes anywhere -> fixed point
    if (tid==0) wflag=0;
    __syncthreads();
  }
  // fused label output: out = (c < c1) ? 1 : 0   (== (c2 < c1))
  {
    size_t base=(size_t)(by+(w<<3))*WW + bx + x0;
    #pragma unroll
    for (int j=0;j<8;++j){
      float2 o; o.x=(v2a[j]<v1a[j])?1.0f:0.0f; o.y=(v2b[j]<v1b[j])?1.0f:0.0f;
      *(float2*)(outg+base)=o;
      base+=(size_t)WW;
    }
  }
}

extern "C" void kernel_launch(void* const* d_in, const int* in_sizes, int n_in,
                              void* d_out, int out_size, void* d_ws, size_t ws_size,
                              hipStream_t stream)
{
  const float* img=(const float*)d_in[0];
  float* out=(float*)d_out;
  char* wsb=(char*)d_ws;
  float* gray=(float*)wsb;
  float* c1  =(float*)(wsb + (size_t)NPX*4);   // doubles as fr cache before init_cost
  unsigned* meta=(unsigned*)(wsb + (size_t)NPX*8);
  float* c2 = out;   // field-2 state lives in d_out (fully rewritten each launch)

  unsigned* hist1=meta;            // 2048
  unsigned* hist2=meta+2048;       // 4*2048
  unsigned* hist3=meta+10240;      // 4*1024
  unsigned* sel1 =meta+14336;
  unsigned* rem1 =meta+14340;
  unsigned* sel2 =meta+14344;
  unsigned* rem2 =meta+14348;
  float*    scal =(float*)(meta+14352);   // 2
  int*      flagIt=(int*)(meta+14354);    // 1  -> total 14355 u32

  hipMemsetAsync(meta, 0, 14355*sizeof(unsigned), stream);
  hipLaunchKernelGGL(gray_kernel, dim3(4096), dim3(256), 0, stream, img, gray);
  hipLaunchKernelGGL(sobel_hist1, dim3(1024), dim3(256), 0, stream, gray, c1, hist1);
  hipLaunchKernelGGL(scan_l1, dim3(1), dim3(1024), 0, stream, hist1, sel1, rem1);
  hipLaunchKernelGGL(hist_l2, dim3(1024), dim3(256), 0, stream, c1, sel1, hist2);
  hipLaunchKernelGGL(scan_l2, dim3(1), dim3(1024), 0, stream, hist2, rem1, sel2, rem2);
  hipLaunchKernelGGL(hist_l3, dim3(1024), dim3(256), 0, stream, c1, sel1, sel2, hist3);
  hipLaunchKernelGGL(scan_l3, dim3(1), dim3(1024), 0, stream, hist3, sel1, sel2, rem2, scal);
  hipLaunchKernelGGL(init_cost, dim3(4096), dim3(256), 0, stream, gray, c1, scal, c1, c2);

  // one-pass local pre-solve (64x64 outputs, 32px-halo windows)
  hipLaunchKernelGGL(tile_solve, dim3(1024), dim3(1024), 0, stream, c1, c2, gray);

  // cooperative verify + cleanup + fused label output
  void* args[]={ (void*)&c1,(void*)&gray,(void*)&out,(void*)&flagIt };
  (void)hipLaunchCooperativeKernel(ws_solve, dim3(NTL), dim3(1024), args, 0, stream);
}